// Round 4
// baseline (291.286 us; speedup 1.0000x reference)
//
#include <hip/hip_runtime.h>
#include <hip/hip_fp16.h>
#include <math.h>
#include <stdint.h>
#include <stddef.h>

#define NLEVELS 16
#define HSIZE   32768
#define LOGH    15
#define RANKK   4
#define PRIME1  2654435761u
#define PRIME2  805459861u

#define BLK   1024
#define PTS   4                  // points per thread
#define PPB   (BLK * PTS)        // 4096 points per block
#define LGRP  4                  // levels per group (grid.y = 4)

struct ResArr { float v[NLEVELS]; };

typedef __attribute__((address_space(1))) const uint32_t gu32;
typedef __attribute__((address_space(3))) uint32_t lu32;

// ---------------- Kernel 1: materialize LoRA tables as packed fp16x2 ----------------
__global__ void build_tables_k(const float* __restrict__ A, const float* __restrict__ B,
                               uint32_t* __restrict__ T) {
    int i = blockIdx.x * blockDim.x + threadIdx.x;
    if (i >= NLEVELS * HSIZE) return;
    int l = i >> LOGH;
    const float4 a = *reinterpret_cast<const float4*>(A + (size_t)i * RANKK);
    const float* b = B + l * (RANKK * 2);   // [r][f]
    float f0 = a.x * b[0] + a.y * b[2] + a.z * b[4] + a.w * b[6];
    float f1 = a.x * b[1] + a.y * b[3] + a.z * b[5] + a.w * b[7];
    __half2 h = __floats2half2_rn(f0, f1);
    T[i] = *reinterpret_cast<uint32_t*>(&h);
}

// Gather + trilerp one point at one level. lds holds the level table (fp16x2).
__device__ __forceinline__ float2 gather_point(const uint32_t* lds,
                                               float xn0, float xn1, float xn2, float r) {
    float xl0 = xn0 * r, xl1 = xn1 * r, xl2 = xn2 * r;
    float fl0 = floorf(xl0), fl1 = floorf(xl1), fl2 = floorf(xl2);
    float w0 = xl0 - fl0, w1 = xl1 - fl1, w2 = xl2 - fl2;
    uint32_t i0 = (uint32_t)fl0, i1 = (uint32_t)fl1, i2 = (uint32_t)fl2;

    uint32_t hx0 = i0,          hx1 = i0 + 1u;
    uint32_t hy0 = i1 * PRIME1, hy1 = hy0 + PRIME1;   // (i1+1)*P1 mod 2^32
    uint32_t hz0 = i2 * PRIME2, hz1 = hz0 + PRIME2;

    float w0a = 1.0f - w0, w1a = 1.0f - w1, w2a = 1.0f - w2;
    float wxy00 = w0a * w1a, wxy10 = w0 * w1a, wxy01 = w0a * w1, wxy11 = w0 * w1;

    float a0 = 0.0f, a1 = 0.0f;
#pragma unroll
    for (int c = 0; c < 8; ++c) {
        uint32_t h = ((c & 1) ? hx1 : hx0) ^ ((c & 2) ? hy1 : hy0) ^ ((c & 4) ? hz1 : hz0);
        uint32_t pk = lds[h & (HSIZE - 1)];
        __half2 h2 = *reinterpret_cast<__half2*>(&pk);
        float2 f = __half22float2(h2);
        float wxy = (c & 2) ? ((c & 1) ? wxy11 : wxy01) : ((c & 1) ? wxy10 : wxy00);
        float wc = wxy * ((c & 4) ? w2 : w2a);
        a0 = fmaf(f.x, wc, a0);
        a1 = fmaf(f.y, wc, a1);
    }
    return make_float2(a0, a1);
}

// ---------------- Kernel 2: grouped encode, manually unrolled levels ----------------
// grid = (nPoints/PPB, 4). Block (cx,g): points [cx*PPB, +PPB), levels [4g, 4g+4).
// No dynamically-indexed private arrays anywhere: levels are a macro unroll,
// resolutions are float4 components, accumulators are 4 named float2 arrays
// indexed only by the (unrolled) point index.
__global__ __launch_bounds__(BLK) __attribute__((amdgpu_waves_per_eu(4, 4)))
void encode_group_k(const float* __restrict__ x, const uint32_t* __restrict__ T,
                    float* __restrict__ out, int nPoints,
                    float4 r0, float4 r1, float4 r2, float4 r3) {
    __shared__ uint32_t lds[HSIZE];          // 128 KiB -> 1 block/CU (4 waves/EU)
    const int t    = threadIdx.x;
    const int base = blockIdx.x * PPB;
    const int g    = blockIdx.y;
    const int l0   = g * LGRP;

    // uniform select of this group's 4 resolutions (registers only, no memory)
    float4 rg = (g < 2) ? (g == 0 ? r0 : r1) : (g == 2 ? r2 : r3);

    // per-point setup: read x once, keep normalized coords in registers
    float xn0[PTS], xn1[PTS], xn2[PTS];
#pragma unroll
    for (int p = 0; p < PTS; ++p) {
        int n = base + p * BLK + t;
        int m = (n < nPoints) ? n : 0;
        xn0[p] = (x[3 * m + 0] + 1.0f) * 0.5f;   // bit-exact: (x+1)/2
        xn1[p] = (x[3 * m + 1] + 1.0f) * 0.5f;
        xn2[p] = (x[3 * m + 2] + 1.0f) * 0.5f;
    }

    float2 accA[PTS], accB[PTS], accC[PTS], accD[PTS];

#define DO_LEVEL(LI, RV, ACC)                                                          \
    {                                                                                  \
        if (LI > 0) __syncthreads();   /* prior level's gathers complete */            \
        const uint32_t* Tl = T + (size_t)(l0 + LI) * HSIZE;                            \
        _Pragma("unroll")                                                              \
        for (int k = 0; k < HSIZE / (BLK * 4); ++k) {                                  \
            int i = (k * BLK + t) * 4;                                                 \
            __builtin_amdgcn_global_load_lds((gu32*)(Tl + i), (lu32*)(lds + i),        \
                                             16, 0, 0);                                \
        }                                                                              \
        __syncthreads();               /* barrier drains vmcnt -> table ready */       \
        _Pragma("unroll")                                                              \
        for (int p = 0; p < PTS; ++p)                                                  \
            ACC[p] = gather_point(lds, xn0[p], xn1[p], xn2[p], RV);                    \
    }

    DO_LEVEL(0, rg.x, accA)
    DO_LEVEL(1, rg.y, accB)
    DO_LEVEL(2, rg.z, accC)
    DO_LEVEL(3, rg.w, accD)
#undef DO_LEVEL

    // epilogue: each point writes its group's 32 contiguous bytes (sector-aligned)
#pragma unroll
    for (int p = 0; p < PTS; ++p) {
        int n = base + p * BLK + t;
        if (n >= nPoints) continue;
        float* dst = out + (size_t)n * (NLEVELS * 2) + 2 * l0;
        *reinterpret_cast<float4*>(dst)     = make_float4(accA[p].x, accA[p].y, accB[p].x, accB[p].y);
        *reinterpret_cast<float4*>(dst + 4) = make_float4(accC[p].x, accC[p].y, accD[p].x, accD[p].y);
    }
}

// ---------------- Fallback: on-the-fly LoRA dequant, global gather (tiny ws) --------
__global__ void encode_fallback_k(const float* __restrict__ x, const float* __restrict__ A,
                                  const float* __restrict__ B, float* __restrict__ out,
                                  int nPoints, ResArr res) {
    int n = blockIdx.x * blockDim.x + threadIdx.x;
    if (n >= nPoints) return;
    float xn0 = (x[3 * n + 0] + 1.0f) * 0.5f;
    float xn1 = (x[3 * n + 1] + 1.0f) * 0.5f;
    float xn2 = (x[3 * n + 2] + 1.0f) * 0.5f;
    for (int l = 0; l < NLEVELS; ++l) {
        float r = res.v[l];
        float xl0 = xn0 * r, xl1 = xn1 * r, xl2 = xn2 * r;
        float fl0 = floorf(xl0), fl1 = floorf(xl1), fl2 = floorf(xl2);
        float w0 = xl0 - fl0, w1 = xl1 - fl1, w2 = xl2 - fl2;
        uint32_t i0 = (uint32_t)fl0, i1 = (uint32_t)fl1, i2 = (uint32_t)fl2;
        uint32_t hx0 = i0,          hx1 = i0 + 1u;
        uint32_t hy0 = i1 * PRIME1, hy1 = hy0 + PRIME1;
        uint32_t hz0 = i2 * PRIME2, hz1 = hz0 + PRIME2;
        float w0a = 1.0f - w0, w1a = 1.0f - w1, w2a = 1.0f - w2;
        float wxy00 = w0a * w1a, wxy10 = w0 * w1a, wxy01 = w0a * w1, wxy11 = w0 * w1;
        const float* b = B + l * 8;
        float b00 = b[0], b01 = b[1], b10 = b[2], b11 = b[3];
        float b20 = b[4], b21 = b[5], b30 = b[6], b31 = b[7];
        float acc0 = 0.0f, acc1 = 0.0f;
#pragma unroll
        for (int c = 0; c < 8; ++c) {
            uint32_t h = ((c & 1) ? hx1 : hx0) ^ ((c & 2) ? hy1 : hy0) ^ ((c & 4) ? hz1 : hz0);
            uint32_t idx = h & (HSIZE - 1);
            float4 a = *reinterpret_cast<const float4*>(A + ((size_t)l * HSIZE + idx) * RANKK);
            float fe0 = a.x * b00 + a.y * b10 + a.z * b20 + a.w * b30;
            float fe1 = a.x * b01 + a.y * b11 + a.z * b21 + a.w * b31;
            float wxy = (c & 2) ? ((c & 1) ? wxy11 : wxy01) : ((c & 1) ? wxy10 : wxy00);
            float wc = wxy * ((c & 4) ? w2 : w2a);
            acc0 = fmaf(fe0, wc, acc0);
            acc1 = fmaf(fe1, wc, acc1);
        }
        out[(size_t)n * 32 + 2 * l + 0] = acc0;
        out[(size_t)n * 32 + 2 * l + 1] = acc1;
    }
}

extern "C" void kernel_launch(void* const* d_in, const int* in_sizes, int n_in,
                              void* d_out, int out_size, void* d_ws, size_t ws_size,
                              hipStream_t stream) {
    const float* x = (const float*)d_in[0];
    const float* A = (const float*)d_in[1];
    const float* B = (const float*)d_in[2];
    float* out = (float*)d_out;
    int nPoints = in_sizes[0] / 3;

    // numpy's resolution ladder, bit-exact via host double libm:
    // b = exp((log(512)-log(16))/15); res_l = float32(floor(16 * b**l))
    float rv[NLEVELS];
    {
        double b = exp((log(512.0) - log(16.0)) / 15.0);
        for (int l = 0; l < NLEVELS; ++l)
            rv[l] = (float)floor(16.0 * pow(b, (double)l));
    }

    const size_t tblBytes = (size_t)NLEVELS * HSIZE * sizeof(uint32_t);   // 2 MiB

    if (ws_size >= tblBytes) {
        uint32_t* T = (uint32_t*)d_ws;
        int nb1 = (NLEVELS * HSIZE + 255) / 256;
        build_tables_k<<<nb1, 256, 0, stream>>>(A, B, T);
        int chunks = (nPoints + PPB - 1) / PPB;           // 128 for N=524288
        dim3 grid(chunks, NLEVELS / LGRP);                // (128, 4) = 512 blocks
        float4 r0 = make_float4(rv[0],  rv[1],  rv[2],  rv[3]);
        float4 r1 = make_float4(rv[4],  rv[5],  rv[6],  rv[7]);
        float4 r2 = make_float4(rv[8],  rv[9],  rv[10], rv[11]);
        float4 r3 = make_float4(rv[12], rv[13], rv[14], rv[15]);
        encode_group_k<<<grid, BLK, 0, stream>>>(x, T, out, nPoints, r0, r1, r2, r3);
    } else {
        ResArr ra;
        for (int l = 0; l < NLEVELS; ++l) ra.v[l] = rv[l];
        encode_fallback_k<<<(nPoints + 255) / 256, 256, 0, stream>>>(x, A, B, out, nPoints, ra);
    }
}

// Round 5
// 233.300 us; speedup vs baseline: 1.2485x; 1.2485x over previous
//
#include <hip/hip_runtime.h>
#include <hip/hip_fp16.h>
#include <math.h>
#include <stdint.h>
#include <stddef.h>

#define NLEVELS 16
#define HSIZE   32768
#define LOGH    15
#define RANKK   4
#define PRIME1  2654435761u
#define PRIME2  805459861u

#define BLK   1024               // threads per block; PTS=1 point per thread
#define PPB   BLK

struct ResArr { float v[NLEVELS]; };

typedef __attribute__((address_space(1))) const uint32_t gu32;
typedef __attribute__((address_space(3))) uint32_t lu32;

// ---------------- Kernel 1: materialize LoRA tables as packed fp16x2 ----------------
__global__ void build_tables_k(const float* __restrict__ A, const float* __restrict__ B,
                               uint32_t* __restrict__ T) {
    int i = blockIdx.x * blockDim.x + threadIdx.x;
    if (i >= NLEVELS * HSIZE) return;
    int l = i >> LOGH;
    const float4 a = *reinterpret_cast<const float4*>(A + (size_t)i * RANKK);
    const float* b = B + l * (RANKK * 2);   // [r][f]
    float f0 = a.x * b[0] + a.y * b[2] + a.z * b[4] + a.w * b[6];
    float f1 = a.x * b[1] + a.y * b[3] + a.z * b[5] + a.w * b[7];
    __half2 h = __floats2half2_rn(f0, f1);
    T[i] = *reinterpret_cast<uint32_t*>(&h);
}

// Gather + trilerp one point at one level. lds holds the level table (fp16x2).
__device__ __forceinline__ float2 gather_point(const uint32_t* lds,
                                               float xn0, float xn1, float xn2, float r) {
    float xl0 = xn0 * r, xl1 = xn1 * r, xl2 = xn2 * r;
    float fl0 = floorf(xl0), fl1 = floorf(xl1), fl2 = floorf(xl2);
    float w0 = xl0 - fl0, w1 = xl1 - fl1, w2 = xl2 - fl2;
    uint32_t i0 = (uint32_t)fl0, i1 = (uint32_t)fl1, i2 = (uint32_t)fl2;

    uint32_t hx0 = i0,          hx1 = i0 + 1u;
    uint32_t hy0 = i1 * PRIME1, hy1 = hy0 + PRIME1;   // (i1+1)*P1 mod 2^32
    uint32_t hz0 = i2 * PRIME2, hz1 = hz0 + PRIME2;

    float w0a = 1.0f - w0, w1a = 1.0f - w1, w2a = 1.0f - w2;
    float wxy00 = w0a * w1a, wxy10 = w0 * w1a, wxy01 = w0a * w1, wxy11 = w0 * w1;

    float a0 = 0.0f, a1 = 0.0f;
#pragma unroll
    for (int c = 0; c < 8; ++c) {
        uint32_t h = ((c & 1) ? hx1 : hx0) ^ ((c & 2) ? hy1 : hy0) ^ ((c & 4) ? hz1 : hz0);
        uint32_t pk = lds[h & (HSIZE - 1)];
        __half2 h2 = *reinterpret_cast<__half2*>(&pk);
        float2 f = __half22float2(h2);
        float wxy = (c & 2) ? ((c & 1) ? wxy11 : wxy01) : ((c & 1) ? wxy10 : wxy00);
        float wc = wxy * ((c & 4) ? w2 : w2a);
        a0 = fmaf(f.x, wc, a0);
        a1 = fmaf(f.y, wc, a1);
    }
    return make_float2(a0, a1);
}

// ---------------- Kernel 2: all 16 levels per block, PTS=1, full-line writes --------
// grid = nPoints/1024 blocks. Each block: for each level (macro-unrolled), async-stage
// the 128 KiB fp16x2 table into LDS, gather+trilerp its 1024 points, accumulate in
// 16 named float2 registers. Epilogue: each thread writes its point's FULL 128 B
// line (out[n][0..32)) — single block owns the line, no partial-line write-allocate.
__global__ __launch_bounds__(BLK)
void encode_all_k(const float* __restrict__ x, const uint32_t* __restrict__ T,
                  float* __restrict__ out, int nPoints,
                  float4 r0, float4 r1, float4 r2, float4 r3) {
    __shared__ uint32_t lds[HSIZE];          // 128 KiB -> 1 block/CU
    const int t = threadIdx.x;
    const int n = blockIdx.x * PPB + t;
    const int m = (n < nPoints) ? n : 0;

    float xn0 = (x[3 * m + 0] + 1.0f) * 0.5f;   // bit-exact: (x+1)/2
    float xn1 = (x[3 * m + 1] + 1.0f) * 0.5f;
    float xn2 = (x[3 * m + 2] + 1.0f) * 0.5f;

    float2 a00, a01, a02, a03, a04, a05, a06, a07;
    float2 a08, a09, a10, a11, a12, a13, a14, a15;

#define DO_LEVEL(L, RV, ACC)                                                           \
    {                                                                                  \
        if (L > 0) __syncthreads();   /* prior level's gathers complete */             \
        const uint32_t* Tl = T + (size_t)L * HSIZE;                                    \
        _Pragma("unroll")                                                              \
        for (int k = 0; k < HSIZE / (BLK * 4); ++k) {                                  \
            int i = (k * BLK + t) * 4;                                                 \
            __builtin_amdgcn_global_load_lds((gu32*)(Tl + i), (lu32*)(lds + i),        \
                                             16, 0, 0);                                \
        }                                                                              \
        __syncthreads();               /* barrier drains vmcnt -> table ready */       \
        ACC = gather_point(lds, xn0, xn1, xn2, RV);                                    \
    }

    DO_LEVEL(0,  r0.x, a00)  DO_LEVEL(1,  r0.y, a01)
    DO_LEVEL(2,  r0.z, a02)  DO_LEVEL(3,  r0.w, a03)
    DO_LEVEL(4,  r1.x, a04)  DO_LEVEL(5,  r1.y, a05)
    DO_LEVEL(6,  r1.z, a06)  DO_LEVEL(7,  r1.w, a07)
    DO_LEVEL(8,  r2.x, a08)  DO_LEVEL(9,  r2.y, a09)
    DO_LEVEL(10, r2.z, a10)  DO_LEVEL(11, r2.w, a11)
    DO_LEVEL(12, r3.x, a12)  DO_LEVEL(13, r3.y, a13)
    DO_LEVEL(14, r3.z, a14)  DO_LEVEL(15, r3.w, a15)
#undef DO_LEVEL

    if (n >= nPoints) return;
    float4* dst = reinterpret_cast<float4*>(out + (size_t)n * (NLEVELS * 2));
    dst[0] = make_float4(a00.x, a00.y, a01.x, a01.y);
    dst[1] = make_float4(a02.x, a02.y, a03.x, a03.y);
    dst[2] = make_float4(a04.x, a04.y, a05.x, a05.y);
    dst[3] = make_float4(a06.x, a06.y, a07.x, a07.y);
    dst[4] = make_float4(a08.x, a08.y, a09.x, a09.y);
    dst[5] = make_float4(a10.x, a10.y, a11.x, a11.y);
    dst[6] = make_float4(a12.x, a12.y, a13.x, a13.y);
    dst[7] = make_float4(a14.x, a14.y, a15.x, a15.y);
}

// ---------------- Fallback: on-the-fly LoRA dequant, global gather (tiny ws) --------
__global__ void encode_fallback_k(const float* __restrict__ x, const float* __restrict__ A,
                                  const float* __restrict__ B, float* __restrict__ out,
                                  int nPoints, ResArr res) {
    int n = blockIdx.x * blockDim.x + threadIdx.x;
    if (n >= nPoints) return;
    float xn0 = (x[3 * n + 0] + 1.0f) * 0.5f;
    float xn1 = (x[3 * n + 1] + 1.0f) * 0.5f;
    float xn2 = (x[3 * n + 2] + 1.0f) * 0.5f;
    for (int l = 0; l < NLEVELS; ++l) {
        float r = res.v[l];
        float xl0 = xn0 * r, xl1 = xn1 * r, xl2 = xn2 * r;
        float fl0 = floorf(xl0), fl1 = floorf(xl1), fl2 = floorf(xl2);
        float w0 = xl0 - fl0, w1 = xl1 - fl1, w2 = xl2 - fl2;
        uint32_t i0 = (uint32_t)fl0, i1 = (uint32_t)fl1, i2 = (uint32_t)fl2;
        uint32_t hx0 = i0,          hx1 = i0 + 1u;
        uint32_t hy0 = i1 * PRIME1, hy1 = hy0 + PRIME1;
        uint32_t hz0 = i2 * PRIME2, hz1 = hz0 + PRIME2;
        float w0a = 1.0f - w0, w1a = 1.0f - w1, w2a = 1.0f - w2;
        float wxy00 = w0a * w1a, wxy10 = w0 * w1a, wxy01 = w0a * w1, wxy11 = w0 * w1;
        const float* b = B + l * 8;
        float b00 = b[0], b01 = b[1], b10 = b[2], b11 = b[3];
        float b20 = b[4], b21 = b[5], b30 = b[6], b31 = b[7];
        float acc0 = 0.0f, acc1 = 0.0f;
#pragma unroll
        for (int c = 0; c < 8; ++c) {
            uint32_t h = ((c & 1) ? hx1 : hx0) ^ ((c & 2) ? hy1 : hy0) ^ ((c & 4) ? hz1 : hz0);
            uint32_t idx = h & (HSIZE - 1);
            float4 a = *reinterpret_cast<const float4*>(A + ((size_t)l * HSIZE + idx) * RANKK);
            float fe0 = a.x * b00 + a.y * b10 + a.z * b20 + a.w * b30;
            float fe1 = a.x * b01 + a.y * b11 + a.z * b21 + a.w * b31;
            float wxy = (c & 2) ? ((c & 1) ? wxy11 : wxy01) : ((c & 1) ? wxy10 : wxy00);
            float wc = wxy * ((c & 4) ? w2 : w2a);
            acc0 = fmaf(fe0, wc, acc0);
            acc1 = fmaf(fe1, wc, acc1);
        }
        out[(size_t)n * 32 + 2 * l + 0] = acc0;
        out[(size_t)n * 32 + 2 * l + 1] = acc1;
    }
}

extern "C" void kernel_launch(void* const* d_in, const int* in_sizes, int n_in,
                              void* d_out, int out_size, void* d_ws, size_t ws_size,
                              hipStream_t stream) {
    const float* x = (const float*)d_in[0];
    const float* A = (const float*)d_in[1];
    const float* B = (const float*)d_in[2];
    float* out = (float*)d_out;
    int nPoints = in_sizes[0] / 3;

    // numpy's resolution ladder, bit-exact via host double libm:
    // b = exp((log(512)-log(16))/15); res_l = float32(floor(16 * b**l))
    float rv[NLEVELS];
    {
        double b = exp((log(512.0) - log(16.0)) / 15.0);
        for (int l = 0; l < NLEVELS; ++l)
            rv[l] = (float)floor(16.0 * pow(b, (double)l));
    }

    const size_t tblBytes = (size_t)NLEVELS * HSIZE * sizeof(uint32_t);   // 2 MiB

    if (ws_size >= tblBytes) {
        uint32_t* T = (uint32_t*)d_ws;
        int nb1 = (NLEVELS * HSIZE + 255) / 256;
        build_tables_k<<<nb1, 256, 0, stream>>>(A, B, T);
        int blocks = (nPoints + PPB - 1) / PPB;           // 512 for N=524288
        float4 r0 = make_float4(rv[0],  rv[1],  rv[2],  rv[3]);
        float4 r1 = make_float4(rv[4],  rv[5],  rv[6],  rv[7]);
        float4 r2 = make_float4(rv[8],  rv[9],  rv[10], rv[11]);
        float4 r3 = make_float4(rv[12], rv[13], rv[14], rv[15]);
        encode_all_k<<<blocks, BLK, 0, stream>>>(x, T, out, nPoints, r0, r1, r2, r3);
    } else {
        ResArr ra;
        for (int l = 0; l < NLEVELS; ++l) ra.v[l] = rv[l];
        encode_fallback_k<<<(nPoints + 255) / 256, 256, 0, stream>>>(x, A, B, out, nPoints, ra);
    }
}

// Round 6
// 132.536 us; speedup vs baseline: 2.1978x; 1.7603x over previous
//
#include <hip/hip_runtime.h>
#include <hip/hip_fp16.h>
#include <math.h>
#include <stdint.h>
#include <stddef.h>

#define NLEVELS 16
#define HSIZE   32768
#define LOGH    15
#define RANKK   4
#define PRIME1  2654435761u
#define PRIME2  805459861u

#define BLK  1024
#define PPB  32768               // points per encode block (32 per thread)

struct ResArr { float v[NLEVELS]; };

// ---------------- Kernel 1: materialize LoRA tables as packed fp16x2 ----------------
__global__ void build_tables_k(const float* __restrict__ A, const float* __restrict__ B,
                               uint32_t* __restrict__ T) {
    int i = blockIdx.x * blockDim.x + threadIdx.x;
    if (i >= NLEVELS * HSIZE) return;
    int l = i >> LOGH;
    const float4 a = *reinterpret_cast<const float4*>(A + (size_t)i * RANKK);
    const float* b = B + l * (RANKK * 2);   // [r][f]
    float f0 = a.x * b[0] + a.y * b[2] + a.z * b[4] + a.w * b[6];
    float f1 = a.x * b[1] + a.y * b[3] + a.z * b[5] + a.w * b[7];
    __half2 h = __floats2half2_rn(f0, f1);
    T[i] = *reinterpret_cast<uint32_t*>(&h);
}

// ---------------- Kernel 2: per-(level, chunk) encode, LDS-resident table ----------
// grid.x = chunks*16 ; level = bx & 15, chunk = bx >> 4. PPB=32768 points/block:
// one 128 KiB table stage amortized over 32768 points (4 B staged per point-level).
// Staging is plain VGPR round-trip (uint4 load + LDS store) — the R1 path with
// exact/clean TCC counters. Results written per level immediately (register-light,
// VGPR ~52): fp16x2 to outT[l][n] (mode 0) or fp32 pair to out[n][32] (mode 1).
__global__ __launch_bounds__(BLK)
void encode_level_k(const float* __restrict__ x, const uint32_t* __restrict__ T,
                    void* __restrict__ dst_base, int nPoints, int directOut,
                    ResArr res) {
    __shared__ uint32_t lds[HSIZE];          // 128 KiB -> 1 block/CU
    const int l     = blockIdx.x & (NLEVELS - 1);
    const int chunk = blockIdx.x >> 4;
    const int t     = threadIdx.x;

    // stage the whole level table into LDS, 16 B per lane per iter (8 iters)
    {
        const uint4* Tl4 = reinterpret_cast<const uint4*>(T + (size_t)l * HSIZE);
        uint4* lds4 = reinterpret_cast<uint4*>(lds);
#pragma unroll
        for (int k = 0; k < HSIZE / 4 / BLK; ++k)
            lds4[k * BLK + t] = Tl4[k * BLK + t];
    }
    __syncthreads();

    const float r = res.v[l];
    const int base = chunk * PPB;
    __half2* outTh = reinterpret_cast<__half2*>(dst_base);   // mode 0: [l][n] half2
    float*   outF  = reinterpret_cast<float*>(dst_base);     // mode 1: [n][32] fp32

    for (int k = 0; k < PPB; k += BLK) {
        int n = base + k + t;
        if (n >= nPoints) break;
        // bit-exact replication of reference fp32 grid math
        float xn0 = (x[3 * n + 0] + 1.0f) * 0.5f;
        float xn1 = (x[3 * n + 1] + 1.0f) * 0.5f;
        float xn2 = (x[3 * n + 2] + 1.0f) * 0.5f;
        float xl0 = xn0 * r, xl1 = xn1 * r, xl2 = xn2 * r;
        float fl0 = floorf(xl0), fl1 = floorf(xl1), fl2 = floorf(xl2);
        float w0 = xl0 - fl0, w1 = xl1 - fl1, w2 = xl2 - fl2;
        uint32_t i0 = (uint32_t)fl0, i1 = (uint32_t)fl1, i2 = (uint32_t)fl2;

        uint32_t hx0 = i0,          hx1 = i0 + 1u;
        uint32_t hy0 = i1 * PRIME1, hy1 = hy0 + PRIME1;   // (i1+1)*P1 mod 2^32
        uint32_t hz0 = i2 * PRIME2, hz1 = hz0 + PRIME2;

        float w0a = 1.0f - w0, w1a = 1.0f - w1, w2a = 1.0f - w2;
        float wxy00 = w0a * w1a, wxy10 = w0 * w1a, wxy01 = w0a * w1, wxy11 = w0 * w1;

        float a0 = 0.0f, a1 = 0.0f;
#pragma unroll
        for (int c = 0; c < 8; ++c) {
            uint32_t h = ((c & 1) ? hx1 : hx0) ^ ((c & 2) ? hy1 : hy0) ^ ((c & 4) ? hz1 : hz0);
            uint32_t pk = lds[h & (HSIZE - 1)];
            __half2 h2 = *reinterpret_cast<__half2*>(&pk);
            float2 f = __half22float2(h2);
            float wxy = (c & 2) ? ((c & 1) ? wxy11 : wxy01) : ((c & 1) ? wxy10 : wxy00);
            float wc = wxy * ((c & 4) ? w2 : w2a);
            a0 = fmaf(f.x, wc, a0);
            a1 = fmaf(f.y, wc, a1);
        }
        if (directOut) {
            *reinterpret_cast<float2*>(outF + (size_t)n * 32 + 2 * l) = make_float2(a0, a1);
        } else {
            outTh[(size_t)l * nPoints + n] = __floats2half2_rn(a0, a1);
        }
    }
}

// ---------------- Kernel 3: merge fp16 outT[l][n] -> fp32 out[n][32] ----------------
__global__ __launch_bounds__(256)
void merge_k(const __half2* __restrict__ outTh, float* __restrict__ out, int nPoints) {
    int n = blockIdx.x * blockDim.x + threadIdx.x;
    if (n >= nPoints) return;
    float4 o[8];
#pragma unroll
    for (int q = 0; q < 8; ++q) {
        float2 a = __half22float2(outTh[(size_t)(2 * q)     * nPoints + n]);  // coalesced
        float2 b = __half22float2(outTh[(size_t)(2 * q + 1) * nPoints + n]);
        o[q] = make_float4(a.x, a.y, b.x, b.y);
    }
    float4* dstv = reinterpret_cast<float4*>(out + (size_t)n * 32);
#pragma unroll
    for (int q = 0; q < 8; ++q) dstv[q] = o[q];
}

// ---------------- Fallback: on-the-fly LoRA dequant, global gather (tiny ws) --------
__global__ void encode_fallback_k(const float* __restrict__ x, const float* __restrict__ A,
                                  const float* __restrict__ B, float* __restrict__ out,
                                  int nPoints, ResArr res) {
    int n = blockIdx.x * blockDim.x + threadIdx.x;
    if (n >= nPoints) return;
    float xn0 = (x[3 * n + 0] + 1.0f) * 0.5f;
    float xn1 = (x[3 * n + 1] + 1.0f) * 0.5f;
    float xn2 = (x[3 * n + 2] + 1.0f) * 0.5f;
    for (int l = 0; l < NLEVELS; ++l) {
        float r = res.v[l];
        float xl0 = xn0 * r, xl1 = xn1 * r, xl2 = xn2 * r;
        float fl0 = floorf(xl0), fl1 = floorf(xl1), fl2 = floorf(xl2);
        float w0 = xl0 - fl0, w1 = xl1 - fl1, w2 = xl2 - fl2;
        uint32_t i0 = (uint32_t)fl0, i1 = (uint32_t)fl1, i2 = (uint32_t)fl2;
        uint32_t hx0 = i0,          hx1 = i0 + 1u;
        uint32_t hy0 = i1 * PRIME1, hy1 = hy0 + PRIME1;
        uint32_t hz0 = i2 * PRIME2, hz1 = hz0 + PRIME2;
        float w0a = 1.0f - w0, w1a = 1.0f - w1, w2a = 1.0f - w2;
        float wxy00 = w0a * w1a, wxy10 = w0 * w1a, wxy01 = w0a * w1, wxy11 = w0 * w1;
        const float* b = B + l * 8;
        float b00 = b[0], b01 = b[1], b10 = b[2], b11 = b[3];
        float b20 = b[4], b21 = b[5], b30 = b[6], b31 = b[7];
        float acc0 = 0.0f, acc1 = 0.0f;
#pragma unroll
        for (int c = 0; c < 8; ++c) {
            uint32_t h = ((c & 1) ? hx1 : hx0) ^ ((c & 2) ? hy1 : hy0) ^ ((c & 4) ? hz1 : hz0);
            uint32_t idx = h & (HSIZE - 1);
            float4 a = *reinterpret_cast<const float4*>(A + ((size_t)l * HSIZE + idx) * RANKK);
            float fe0 = a.x * b00 + a.y * b10 + a.z * b20 + a.w * b30;
            float fe1 = a.x * b01 + a.y * b11 + a.z * b21 + a.w * b31;
            float wxy = (c & 2) ? ((c & 1) ? wxy11 : wxy01) : ((c & 1) ? wxy10 : wxy00);
            float wc = wxy * ((c & 4) ? w2 : w2a);
            acc0 = fmaf(fe0, wc, acc0);
            acc1 = fmaf(fe1, wc, acc1);
        }
        out[(size_t)n * 32 + 2 * l + 0] = acc0;
        out[(size_t)n * 32 + 2 * l + 1] = acc1;
    }
}

extern "C" void kernel_launch(void* const* d_in, const int* in_sizes, int n_in,
                              void* d_out, int out_size, void* d_ws, size_t ws_size,
                              hipStream_t stream) {
    const float* x = (const float*)d_in[0];
    const float* A = (const float*)d_in[1];
    const float* B = (const float*)d_in[2];
    float* out = (float*)d_out;
    int nPoints = in_sizes[0] / 3;

    // numpy's resolution ladder, bit-exact via host double libm:
    // b = exp((log(512)-log(16))/15); res_l = float32(floor(16 * b**l))
    ResArr ra;
    {
        double b = exp((log(512.0) - log(16.0)) / 15.0);
        for (int l = 0; l < NLEVELS; ++l)
            ra.v[l] = (float)floor(16.0 * pow(b, (double)l));
    }

    const size_t tblBytes  = (size_t)NLEVELS * HSIZE * sizeof(uint32_t);             // 2 MiB
    const size_t outTBytes = (size_t)NLEVELS * (size_t)nPoints * sizeof(__half2);    // 32 MiB

    if (ws_size >= tblBytes) {
        uint32_t* T = (uint32_t*)d_ws;
        int nb1 = (NLEVELS * HSIZE + 255) / 256;
        build_tables_k<<<nb1, 256, 0, stream>>>(A, B, T);
        int chunks = (nPoints + PPB - 1) / PPB;           // 16 for N=524288
        if (ws_size >= tblBytes + outTBytes) {
            void* outT = (void*)((char*)d_ws + tblBytes);
            encode_level_k<<<chunks * NLEVELS, BLK, 0, stream>>>(x, T, outT, nPoints, 0, ra);
            merge_k<<<(nPoints + 255) / 256, 256, 0, stream>>>((const __half2*)outT, out, nPoints);
        } else {
            encode_level_k<<<chunks * NLEVELS, BLK, 0, stream>>>(x, T, (void*)out, nPoints, 1, ra);
        }
    } else {
        encode_fallback_k<<<(nPoints + 255) / 256, 256, 0, stream>>>(x, A, B, out, nPoints, ra);
    }
}

// Round 7
// 132.336 us; speedup vs baseline: 2.2011x; 1.0015x over previous
//
#include <hip/hip_runtime.h>
#include <hip/hip_fp16.h>
#include <math.h>
#include <stdint.h>
#include <stddef.h>

#define NLEVELS 16
#define HSIZE   32768
#define LOGH    15
#define RANKK   4
#define PRIME1  2654435761u
#define PRIME2  805459861u

#define BLK  1024
#define PPB  32768               // points per encode block (32 per thread)

struct ResArr { float v[NLEVELS]; };

// ---------------- Kernel 1: materialize LoRA tables as packed fp16x2 ----------------
__global__ void build_tables_k(const float* __restrict__ A, const float* __restrict__ B,
                               uint32_t* __restrict__ T) {
    int i = blockIdx.x * blockDim.x + threadIdx.x;
    if (i >= NLEVELS * HSIZE) return;
    int l = i >> LOGH;
    const float4 a = *reinterpret_cast<const float4*>(A + (size_t)i * RANKK);
    const float* b = B + l * (RANKK * 2);   // [r][f]
    float f0 = a.x * b[0] + a.y * b[2] + a.z * b[4] + a.w * b[6];
    float f1 = a.x * b[1] + a.y * b[3] + a.z * b[5] + a.w * b[7];
    __half2 h = __floats2half2_rn(f0, f1);
    T[i] = *reinterpret_cast<uint32_t*>(&h);
}

// ---------------- Kernel 2: per-(level, chunk) encode, LDS-resident table ----------
// grid.x = chunks*16 ; level = bx & 15, chunk = bx >> 4. PPB=32768 points/block
// (4 B staged per point-level). 2 points per thread per iteration, macro-unrolled,
// so ~16 independent LDS gathers are in flight between dependency stalls.
__global__ __launch_bounds__(BLK) __attribute__((amdgpu_waves_per_eu(4, 4)))
void encode_level_k(const float* __restrict__ x, const uint32_t* __restrict__ T,
                    void* __restrict__ dst_base, int nPoints, int directOut,
                    ResArr res) {
    __shared__ uint32_t lds[HSIZE];          // 128 KiB -> 1 block/CU (4 waves/EU)
    const int l     = blockIdx.x & (NLEVELS - 1);
    const int chunk = blockIdx.x >> 4;
    const int t     = threadIdx.x;

    // stage the whole level table into LDS, 16 B per lane per iter (8 iters)
    {
        const uint4* Tl4 = reinterpret_cast<const uint4*>(T + (size_t)l * HSIZE);
        uint4* lds4 = reinterpret_cast<uint4*>(lds);
#pragma unroll
        for (int k = 0; k < HSIZE / 4 / BLK; ++k)
            lds4[k * BLK + t] = Tl4[k * BLK + t];
    }
    __syncthreads();

    const float r = res.v[l];
    const int base = chunk * PPB;
    __half2* outTh = reinterpret_cast<__half2*>(dst_base);   // mode 0: [l][n] half2
    float*   outF  = reinterpret_cast<float*>(dst_base);     // mode 1: [n][32] fp32

    for (int k = 0; k < PPB; k += 2 * BLK) {
        int   n[2];
        bool  ok[2];
        float acc0[2], acc1[2];
        float w2v[2], w2a_[2];
        float wxy00[2], wxy10[2], wxy01[2], wxy11[2];
        uint32_t hx0[2], hx1[2], hy0[2], hy1[2], hz0[2], hz1[2];

#pragma unroll
        for (int u = 0; u < 2; ++u) {
            n[u]  = base + k + u * BLK + t;
            ok[u] = (n[u] < nPoints);
            int m = ok[u] ? n[u] : 0;
            // bit-exact replication of reference fp32 grid math
            float xn0 = (x[3 * m + 0] + 1.0f) * 0.5f;
            float xn1 = (x[3 * m + 1] + 1.0f) * 0.5f;
            float xn2 = (x[3 * m + 2] + 1.0f) * 0.5f;
            float xl0 = xn0 * r, xl1 = xn1 * r, xl2 = xn2 * r;
            float fl0 = floorf(xl0), fl1 = floorf(xl1), fl2 = floorf(xl2);
            float w0 = xl0 - fl0, w1 = xl1 - fl1, w2 = xl2 - fl2;
            uint32_t i0 = (uint32_t)fl0, i1 = (uint32_t)fl1, i2 = (uint32_t)fl2;

            hx0[u] = i0;          hx1[u] = i0 + 1u;
            hy0[u] = i1 * PRIME1; hy1[u] = hy0[u] + PRIME1;   // (i1+1)*P1 mod 2^32
            hz0[u] = i2 * PRIME2; hz1[u] = hz0[u] + PRIME2;

            float w0a = 1.0f - w0, w1a = 1.0f - w1;
            w2v[u] = w2; w2a_[u] = 1.0f - w2;
            wxy00[u] = w0a * w1a; wxy10[u] = w0 * w1a;
            wxy01[u] = w0a * w1;  wxy11[u] = w0 * w1;
            acc0[u] = 0.0f; acc1[u] = 0.0f;
        }

        // 16 independent gathers (8 per point, 2 points) — compiler interleaves
#pragma unroll
        for (int c = 0; c < 8; ++c) {
#pragma unroll
            for (int u = 0; u < 2; ++u) {
                uint32_t h = ((c & 1) ? hx1[u] : hx0[u]) ^ ((c & 2) ? hy1[u] : hy0[u])
                           ^ ((c & 4) ? hz1[u] : hz0[u]);
                uint32_t pk = lds[h & (HSIZE - 1)];
                __half2 h2 = *reinterpret_cast<__half2*>(&pk);
                float2 f = __half22float2(h2);
                float wxy = (c & 2) ? ((c & 1) ? wxy11[u] : wxy01[u])
                                    : ((c & 1) ? wxy10[u] : wxy00[u]);
                float wc = wxy * ((c & 4) ? w2v[u] : w2a_[u]);
                acc0[u] = fmaf(f.x, wc, acc0[u]);
                acc1[u] = fmaf(f.y, wc, acc1[u]);
            }
        }

#pragma unroll
        for (int u = 0; u < 2; ++u) {
            if (!ok[u]) continue;
            if (directOut) {
                *reinterpret_cast<float2*>(outF + (size_t)n[u] * 32 + 2 * l) =
                    make_float2(acc0[u], acc1[u]);
            } else {
                outTh[(size_t)l * nPoints + n[u]] = __floats2half2_rn(acc0[u], acc1[u]);
            }
        }
    }
}

// ---------------- Kernel 3: merge fp16 outT[l][n] -> fp32 out[n][32] ----------------
// 2 points per thread: 8 B loads per level stream, two full 128 B lines out.
__global__ __launch_bounds__(256)
void merge_k(const __half2* __restrict__ outTh, float* __restrict__ out, int nPoints) {
    int p2 = blockIdx.x * blockDim.x + threadIdx.x;   // pair index
    int n0 = 2 * p2;
    if (n0 >= nPoints) return;
    bool has1 = (n0 + 1) < nPoints;

    float4 oA[8], oB[8];
#pragma unroll
    for (int q = 0; q < 8; ++q) {
        // two consecutive points from streams 2q and 2q+1 (8 B coalesced loads)
        __half2 s0[2], s1[2];
        *reinterpret_cast<uint2*>(s0) =
            *reinterpret_cast<const uint2*>(outTh + (size_t)(2 * q) * nPoints + n0);
        *reinterpret_cast<uint2*>(s1) =
            *reinterpret_cast<const uint2*>(outTh + (size_t)(2 * q + 1) * nPoints + n0);
        float2 a0 = __half22float2(s0[0]), a1 = __half22float2(s0[1]);
        float2 b0 = __half22float2(s1[0]), b1 = __half22float2(s1[1]);
        oA[q] = make_float4(a0.x, a0.y, b0.x, b0.y);
        oB[q] = make_float4(a1.x, a1.y, b1.x, b1.y);
    }
    float4* dstA = reinterpret_cast<float4*>(out + (size_t)n0 * 32);
#pragma unroll
    for (int q = 0; q < 8; ++q) dstA[q] = oA[q];
    if (has1) {
        float4* dstB = reinterpret_cast<float4*>(out + (size_t)(n0 + 1) * 32);
#pragma unroll
        for (int q = 0; q < 8; ++q) dstB[q] = oB[q];
    }
}

// ---------------- Fallback: on-the-fly LoRA dequant, global gather (tiny ws) --------
__global__ void encode_fallback_k(const float* __restrict__ x, const float* __restrict__ A,
                                  const float* __restrict__ B, float* __restrict__ out,
                                  int nPoints, ResArr res) {
    int n = blockIdx.x * blockDim.x + threadIdx.x;
    if (n >= nPoints) return;
    float xn0 = (x[3 * n + 0] + 1.0f) * 0.5f;
    float xn1 = (x[3 * n + 1] + 1.0f) * 0.5f;
    float xn2 = (x[3 * n + 2] + 1.0f) * 0.5f;
    for (int l = 0; l < NLEVELS; ++l) {
        float r = res.v[l];
        float xl0 = xn0 * r, xl1 = xn1 * r, xl2 = xn2 * r;
        float fl0 = floorf(xl0), fl1 = floorf(xl1), fl2 = floorf(xl2);
        float w0 = xl0 - fl0, w1 = xl1 - fl1, w2 = xl2 - fl2;
        uint32_t i0 = (uint32_t)fl0, i1 = (uint32_t)fl1, i2 = (uint32_t)fl2;
        uint32_t hx0 = i0,          hx1 = i0 + 1u;
        uint32_t hy0 = i1 * PRIME1, hy1 = hy0 + PRIME1;
        uint32_t hz0 = i2 * PRIME2, hz1 = hz0 + PRIME2;
        float w0a = 1.0f - w0, w1a = 1.0f - w1, w2a = 1.0f - w2;
        float wxy00 = w0a * w1a, wxy10 = w0 * w1a, wxy01 = w0a * w1, wxy11 = w0 * w1;
        const float* b = B + l * 8;
        float b00 = b[0], b01 = b[1], b10 = b[2], b11 = b[3];
        float b20 = b[4], b21 = b[5], b30 = b[6], b31 = b[7];
        float acc0 = 0.0f, acc1 = 0.0f;
#pragma unroll
        for (int c = 0; c < 8; ++c) {
            uint32_t h = ((c & 1) ? hx1 : hx0) ^ ((c & 2) ? hy1 : hy0) ^ ((c & 4) ? hz1 : hz0);
            uint32_t idx = h & (HSIZE - 1);
            float4 a = *reinterpret_cast<const float4*>(A + ((size_t)l * HSIZE + idx) * RANKK);
            float fe0 = a.x * b00 + a.y * b10 + a.z * b20 + a.w * b30;
            float fe1 = a.x * b01 + a.y * b11 + a.z * b21 + a.w * b31;
            float wxy = (c & 2) ? ((c & 1) ? wxy11 : wxy01) : ((c & 1) ? wxy10 : wxy00);
            float wc = wxy * ((c & 4) ? w2 : w2a);
            acc0 = fmaf(fe0, wc, acc0);
            acc1 = fmaf(fe1, wc, acc1);
        }
        out[(size_t)n * 32 + 2 * l + 0] = acc0;
        out[(size_t)n * 32 + 2 * l + 1] = acc1;
    }
}

extern "C" void kernel_launch(void* const* d_in, const int* in_sizes, int n_in,
                              void* d_out, int out_size, void* d_ws, size_t ws_size,
                              hipStream_t stream) {
    const float* x = (const float*)d_in[0];
    const float* A = (const float*)d_in[1];
    const float* B = (const float*)d_in[2];
    float* out = (float*)d_out;
    int nPoints = in_sizes[0] / 3;

    // numpy's resolution ladder, bit-exact via host double libm:
    // b = exp((log(512)-log(16))/15); res_l = float32(floor(16 * b**l))
    ResArr ra;
    {
        double b = exp((log(512.0) - log(16.0)) / 15.0);
        for (int l = 0; l < NLEVELS; ++l)
            ra.v[l] = (float)floor(16.0 * pow(b, (double)l));
    }

    const size_t tblBytes  = (size_t)NLEVELS * HSIZE * sizeof(uint32_t);             // 2 MiB
    const size_t outTBytes = (size_t)NLEVELS * (size_t)nPoints * sizeof(__half2);    // 32 MiB

    if (ws_size >= tblBytes) {
        uint32_t* T = (uint32_t*)d_ws;
        int nb1 = (NLEVELS * HSIZE + 255) / 256;
        build_tables_k<<<nb1, 256, 0, stream>>>(A, B, T);
        int chunks = (nPoints + PPB - 1) / PPB;           // 16 for N=524288
        if (ws_size >= tblBytes + outTBytes) {
            void* outT = (void*)((char*)d_ws + tblBytes);
            encode_level_k<<<chunks * NLEVELS, BLK, 0, stream>>>(x, T, outT, nPoints, 0, ra);
            int pairs = (nPoints + 1) / 2;
            merge_k<<<(pairs + 255) / 256, 256, 0, stream>>>((const __half2*)outT, out, nPoints);
        } else {
            encode_level_k<<<chunks * NLEVELS, BLK, 0, stream>>>(x, T, (void*)out, nPoints, 1, ra);
        }
    } else {
        encode_fallback_k<<<(nPoints + 255) / 256, 256, 0, stream>>>(x, A, B, out, nPoints, ra);
    }
}